// Round 1
// baseline (186.331 us; speedup 1.0000x reference)
//
#include <hip/hip_runtime.h>

#define IOU_THR 0.7f

// ---------------------------------------------------------------------------
// Kernel 1: compute stable descending-sort rank of each score via O(N^2)
// key-count, scatter box to its sorted slot, and zero the suppression mask.
// key = (~score_bits << 32) | index  -> ascending u64 order == descending
// score with ascending-index tie-break (matches stable jnp.argsort(-score)).
// ---------------------------------------------------------------------------
__global__ void nms_rank_kernel(const float* __restrict__ score,
                                const float4* __restrict__ bbox,
                                float4* __restrict__ sortedBox,
                                unsigned int* __restrict__ mask,
                                int N)
{
    __shared__ unsigned long long skeys[256];
    const int i = blockIdx.x * 256 + threadIdx.x;
    const unsigned int sb = __float_as_uint(score[i]);
    const unsigned long long mykey =
        (((unsigned long long)(~sb)) << 32) | (unsigned int)i;

    int rank = 0;
    for (int t = 0; t < N; t += 256) {
        const unsigned int ob = __float_as_uint(score[t + (int)threadIdx.x]);
        skeys[threadIdx.x] =
            (((unsigned long long)(~ob)) << 32) | (unsigned int)(t + threadIdx.x);
        __syncthreads();
        #pragma unroll 8
        for (int k = 0; k < 256; ++k)
            rank += (skeys[k] < mykey) ? 1 : 0;
        __syncthreads();
    }
    sortedBox[rank] = bbox[i];
    mask[i] = 0u;   // zero mask for kernel 2 (d_ws is NOT re-poisoned to 0)
}

// ---------------------------------------------------------------------------
// Kernel 2: suppressed[j] |= any i<j with IoU(b_i, b_j) > 0.7.
// Grid (i-tile, j-tile), i-tile staged in LDS; atomicOr partial results.
// Box layout: (y1, x1, y2, x2) = (b.x, b.y, b.z, b.w).
// ---------------------------------------------------------------------------
__global__ void nms_suppress_kernel(const float4* __restrict__ sortedBox,
                                    unsigned int* __restrict__ mask)
{
    const int bi = blockIdx.x;   // i tile
    const int bj = blockIdx.y;   // j tile
    if (bi > bj) return;         // only i < j contributes

    __shared__ float4 tile[256];
    const int tid = threadIdx.x;
    const int j = bj * 256 + tid;

    const float4 bb = sortedBox[j];
    const float aj = (bb.z - bb.x) * (bb.w - bb.y);
    tile[tid] = sortedBox[bi * 256 + tid];
    __syncthreads();

    const int limit = (bi == bj) ? tid : 256;
    unsigned int sup = 0u;
    for (int k = 0; k < limit; ++k) {
        const float4 bo = tile[k];
        const float ai = (bo.z - bo.x) * (bo.w - bo.y);
        const float iy1 = fmaxf(bo.x, bb.x);
        const float ix1 = fmaxf(bo.y, bb.y);
        const float iy2 = fminf(bo.z, bb.z);
        const float ix2 = fminf(bo.w, bb.w);
        const float ih = fmaxf(iy2 - iy1, 0.0f);
        const float iw = fmaxf(ix2 - ix1, 0.0f);
        float inter = ih * iw;
        // Block FMA contraction so union rounds exactly like numpy:
        // ((ai + aj) - inter), each op individually rounded.
        asm volatile("" : "+v"(inter));
        float s = ai + aj;
        asm volatile("" : "+v"(s));
        const float uni = s - inter;
        // IEEE-correct f32 division (no fast-math) matches np rounding.
        sup |= (inter / uni > IOU_THR) ? 1u : 0u;
    }
    if (sup) atomicOr(&mask[j], 1u);
}

// ---------------------------------------------------------------------------
// Kernel 3: keep = !suppressed; write masked sorted boxes + keep flags.
// d_out layout: [N*4 floats boxes][N floats keep].
// ---------------------------------------------------------------------------
__global__ void nms_output_kernel(const float4* __restrict__ sortedBox,
                                  const unsigned int* __restrict__ mask,
                                  float* __restrict__ out, int N)
{
    const int j = blockIdx.x * 256 + threadIdx.x;
    const float s = (mask[j] == 0u) ? 1.0f : 0.0f;
    const float4 b = sortedBox[j];
    float4 o;
    o.x = b.x * s; o.y = b.y * s; o.z = b.z * s; o.w = b.w * s;
    ((float4*)out)[j] = o;
    out[N * 4 + j] = s;
}

extern "C" void kernel_launch(void* const* d_in, const int* in_sizes, int n_in,
                              void* d_out, int out_size, void* d_ws, size_t ws_size,
                              hipStream_t stream) {
    const float* bbox  = (const float*)d_in[0];   // [1, N, 4]
    const float* score = (const float*)d_in[1];   // [1, N]
    const int N = in_sizes[1];                    // 8192

    float4* sortedBox   = (float4*)d_ws;                               // N * 16 B
    unsigned int* mask  = (unsigned int*)((char*)d_ws + (size_t)N * sizeof(float4)); // N * 4 B

    const int nb = N / 256;
    nms_rank_kernel<<<nb, 256, 0, stream>>>(score, (const float4*)bbox,
                                            sortedBox, mask, N);
    dim3 g2(nb, nb);
    nms_suppress_kernel<<<g2, 256, 0, stream>>>(sortedBox, mask);
    nms_output_kernel<<<nb, 256, 0, stream>>>(sortedBox, mask, (float*)d_out, N);
}

// Round 2
// 59.708 us; speedup vs baseline: 3.1207x; 3.1207x over previous
//
#include <hip/hip_runtime.h>

#define IOU_THR 0.7f

__device__ __forceinline__ unsigned long long make_key(unsigned int sbits,
                                                       unsigned int idx) {
    // descending score, ascending index tie-break (stable argsort(-score))
    return (((unsigned long long)(~sbits)) << 32) | idx;
}

// ---------------------------------------------------------------------------
// Kernel A: partial rank counts. grid = (N/512, N/256), block = 256.
// Each thread owns TWO i-keys (registers); block processes one 256-key tile
// staged in LDS; partial counts accumulate via atomicAdd into rank[].
// ---------------------------------------------------------------------------
__global__ void nms_rank_partial(const float* __restrict__ score,
                                 unsigned int* __restrict__ rank, int N)
{
    __shared__ unsigned long long skeys[256];
    const int tid = threadIdx.x;
    const int i0  = blockIdx.x * 512 + tid;
    const int i1  = i0 + 256;
    const int t   = blockIdx.y * 256 + tid;

    skeys[tid] = make_key(__float_as_uint(score[t]), (unsigned int)t);

    const unsigned long long k0 =
        make_key(__float_as_uint(score[i0]), (unsigned int)i0);
    const unsigned long long k1 =
        make_key(__float_as_uint(score[i1]), (unsigned int)i1);
    __syncthreads();

    unsigned int c0 = 0, c1 = 0;
    #pragma unroll 8
    for (int k = 0; k < 256; ++k) {
        const unsigned long long ok = skeys[k];
        c0 += (ok < k0) ? 1u : 0u;
        c1 += (ok < k1) ? 1u : 0u;
    }
    atomicAdd(&rank[i0], c0);
    atomicAdd(&rank[i1], c1);
}

// ---------------------------------------------------------------------------
// Kernel B: scatter box + its area to the sorted slot.
// ---------------------------------------------------------------------------
__global__ void nms_scatter(const float4* __restrict__ bbox,
                            const unsigned int* __restrict__ rank,
                            float4* __restrict__ sortedBox,
                            float* __restrict__ sortedArea)
{
    const int i = blockIdx.x * 256 + threadIdx.x;
    const unsigned int r = rank[i];
    const float4 b = bbox[i];
    sortedBox[r]  = b;
    sortedArea[r] = (b.z - b.x) * (b.w - b.y);   // (y2-y1)*(x2-x1)
}

// ---------------------------------------------------------------------------
// Kernel C: suppressed[j] |= any i<j with IoU(b_i, b_j) > 0.7.
// Cheap conservative pre-filter (inter > 0.6999*union) gates the exact
// IEEE-division path; margin 1.4e-3 relative >> 1-ulp rounding error, so
// no true positive can be rejected. Most wave-iterations skip the divide
// entirely via execz.
// ---------------------------------------------------------------------------
__global__ void nms_suppress(const float4* __restrict__ sortedBox,
                             const float* __restrict__ sortedArea,
                             unsigned int* __restrict__ mask)
{
    const int bi = blockIdx.x;   // i tile
    const int bj = blockIdx.y;   // j tile
    if (bi > bj) return;

    __shared__ float4 tile[256];
    __shared__ float  tarea[256];
    const int tid = threadIdx.x;
    const int j = bj * 256 + tid;

    const float4 bb = sortedBox[j];
    const float  aj = sortedArea[j];
    tile[tid]  = sortedBox[bi * 256 + tid];
    tarea[tid] = sortedArea[bi * 256 + tid];
    __syncthreads();

    const int limit = (bi == bj) ? tid : 256;
    unsigned int sup = 0u;
    for (int k = 0; k < limit; ++k) {
        const float4 bo = tile[k];
        const float iy1 = fmaxf(bo.x, bb.x);
        const float ix1 = fmaxf(bo.y, bb.y);
        const float iy2 = fminf(bo.z, bb.z);
        const float ix2 = fminf(bo.w, bb.w);
        const float ih  = fmaxf(iy2 - iy1, 0.0f);
        const float iw  = fmaxf(ix2 - ix1, 0.0f);
        float inter = ih * iw;
        const float ai = tarea[k];
        const float uni_est = (ai + aj) - inter;
        if (inter > 0.6999f * uni_est) {
            // exact path: per-op rounding identical to numpy
            asm volatile("" : "+v"(inter));
            float s = ai + aj;
            asm volatile("" : "+v"(s));
            const float uni = s - inter;
            sup |= (inter / uni > IOU_THR) ? 1u : 0u;
        }
    }
    if (sup) atomicOr(&mask[j], 1u);
}

// ---------------------------------------------------------------------------
// Kernel D: keep = !suppressed; write masked sorted boxes + keep flags.
// d_out layout: [N*4 floats boxes][N floats keep].
// ---------------------------------------------------------------------------
__global__ void nms_output(const float4* __restrict__ sortedBox,
                           const unsigned int* __restrict__ mask,
                           float* __restrict__ out, int N)
{
    const int j = blockIdx.x * 256 + threadIdx.x;
    const float s = (mask[j] == 0u) ? 1.0f : 0.0f;
    const float4 b = sortedBox[j];
    float4 o;
    o.x = b.x * s; o.y = b.y * s; o.z = b.z * s; o.w = b.w * s;
    ((float4*)out)[j] = o;
    out[N * 4 + j] = s;
}

extern "C" void kernel_launch(void* const* d_in, const int* in_sizes, int n_in,
                              void* d_out, int out_size, void* d_ws, size_t ws_size,
                              hipStream_t stream) {
    const float* bbox  = (const float*)d_in[0];   // [1, N, 4] (y1,x1,y2,x2)
    const float* score = (const float*)d_in[1];   // [1, N]
    const int N = in_sizes[1];                    // 8192

    char* ws = (char*)d_ws;
    float4*       sortedBox  = (float4*)ws;                             // N*16 B
    float*        sortedArea = (float*)(ws + (size_t)N * 16);           // N*4 B
    unsigned int* rank       = (unsigned int*)(ws + (size_t)N * 20);    // N*4 B
    unsigned int* mask       = (unsigned int*)(ws + (size_t)N * 24);    // N*4 B

    const int nb = N / 256;

    // zero rank + mask (contiguous) — required every call (graph replay)
    hipMemsetAsync(ws + (size_t)N * 20, 0, (size_t)N * 8, stream);

    nms_rank_partial<<<dim3(N / 512, nb), 256, 0, stream>>>(score, rank, N);
    nms_scatter<<<nb, 256, 0, stream>>>((const float4*)bbox, rank,
                                        sortedBox, sortedArea);
    nms_suppress<<<dim3(nb, nb), 256, 0, stream>>>(sortedBox, sortedArea, mask);
    nms_output<<<nb, 256, 0, stream>>>(sortedBox, mask, (float*)d_out, N);
}

// Round 3
// 55.847 us; speedup vs baseline: 3.3365x; 1.0691x over previous
//
#include <hip/hip_runtime.h>

#define IOU_THR 0.7f
#define FILT_C  0.69985f   // conservative filter coeff: 0.7*(1-2e-4)

__device__ __forceinline__ unsigned long long make_key(unsigned int sbits,
                                                       unsigned int idx) {
    // descending score, ascending index tie-break (stable argsort(-score))
    return (((unsigned long long)(~sbits)) << 32) | idx;
}

// ---------------------------------------------------------------------------
// Kernel A: partial rank counts, 4 i-keys per thread.
// grid = (N/1024, N/256), block = 256.
// ---------------------------------------------------------------------------
__global__ void nms_rank_partial(const float* __restrict__ score,
                                 unsigned int* __restrict__ rank, int N)
{
    __shared__ unsigned long long skeys[256];
    const int tid = threadIdx.x;
    const int t   = blockIdx.y * 256 + tid;
    skeys[tid] = make_key(__float_as_uint(score[t]), (unsigned int)t);

    const int i0 = blockIdx.x * 1024 + tid;
    const unsigned long long k0 = make_key(__float_as_uint(score[i0      ]), i0      );
    const unsigned long long k1 = make_key(__float_as_uint(score[i0 + 256]), i0 + 256);
    const unsigned long long k2 = make_key(__float_as_uint(score[i0 + 512]), i0 + 512);
    const unsigned long long k3 = make_key(__float_as_uint(score[i0 + 768]), i0 + 768);
    __syncthreads();

    unsigned int c0 = 0, c1 = 0, c2 = 0, c3 = 0;
    #pragma unroll 8
    for (int k = 0; k < 256; ++k) {
        const unsigned long long ok = skeys[k];
        c0 += (ok < k0) ? 1u : 0u;
        c1 += (ok < k1) ? 1u : 0u;
        c2 += (ok < k2) ? 1u : 0u;
        c3 += (ok < k3) ? 1u : 0u;
    }
    atomicAdd(&rank[i0      ], c0);
    atomicAdd(&rank[i0 + 256], c1);
    atomicAdd(&rank[i0 + 512], c2);
    atomicAdd(&rank[i0 + 768], c3);
}

// ---------------------------------------------------------------------------
// Kernel B: scatter box + area to sorted slot.
// ---------------------------------------------------------------------------
__global__ void nms_scatter(const float4* __restrict__ bbox,
                            const unsigned int* __restrict__ rank,
                            float4* __restrict__ sortedBox,
                            float* __restrict__ sortedArea)
{
    const int i = blockIdx.x * 256 + threadIdx.x;
    const unsigned int r = rank[i];
    const float4 b = bbox[i];
    sortedBox[r]  = b;
    sortedArea[r] = (b.z - b.x) * (b.w - b.y);   // (y2-y1)*(x2-x1)
}

// ---------------------------------------------------------------------------
// Kernel C: suppressed[j] |= any i<j with IoU > 0.7.
// 1D triangular grid over (bi <= bj) tile pairs.
// Off-diagonal: 4 waves split the i-tile (64 each), each lane owns 4 j's ->
// one LDS broadcast feeds 4 pair-evals (VALU-bound, not LDS-bound).
// Diagonal: 1 j per thread, k < tid (rare: 32 of 528 blocks).
// Cheap conservative filter gates the exact IEEE-division path.
// ---------------------------------------------------------------------------
__global__ void nms_suppress(const float4* __restrict__ sortedBox,
                             const float* __restrict__ sortedArea,
                             unsigned int* __restrict__ mask)
{
    // decode triangular index: x = bj*(bj+1)/2 + bi, bi <= bj
    const int x = blockIdx.x;
    int bj = (int)((sqrtf(8.0f * (float)x + 1.0f) - 1.0f) * 0.5f);
    while ((bj + 1) * (bj + 2) / 2 <= x) ++bj;
    while (bj * (bj + 1) / 2 > x) --bj;
    const int bi = x - bj * (bj + 1) / 2;

    __shared__ float4 tile[256];
    __shared__ float  tpai[256];          // FILT_C * area_i
    const int tid = threadIdx.x;

    tile[tid] = sortedBox[bi * 256 + tid];
    tpai[tid] = FILT_C * sortedArea[bi * 256 + tid];
    __syncthreads();

    if (bi == bj) {
        const int j = bj * 256 + tid;
        const float4 bb = sortedBox[j];
        const float  paj = FILT_C * sortedArea[j];
        unsigned int sup = 0u;
        for (int k = 0; k < tid; ++k) {
            const float4 bo = tile[k];
            const float iy1 = fmaxf(bo.x, bb.x);
            const float ix1 = fmaxf(bo.y, bb.y);
            const float iy2 = fminf(bo.z, bb.z);
            const float ix2 = fminf(bo.w, bb.w);
            const float ih  = fmaxf(iy2 - iy1, 0.0f);
            const float iw  = fmaxf(ix2 - ix1, 0.0f);
            float inter = ih * iw;
            if (fmaf(inter, 1.7f, -(tpai[k] + paj)) > 0.0f) {
                // exact path: per-op rounding identical to numpy
                float ai = (bo.z - bo.x) * (bo.w - bo.y);
                float aj = (bb.z - bb.x) * (bb.w - bb.y);
                asm volatile("" : "+v"(ai));
                asm volatile("" : "+v"(aj));
                asm volatile("" : "+v"(inter));
                float s = ai + aj;
                asm volatile("" : "+v"(s));
                const float uni = s - inter;
                sup |= (inter / uni > IOU_THR) ? 1u : 0u;
            }
        }
        if (sup) atomicOr(&mask[j], 1u);
    } else {
        const int w = tid >> 6;           // wave id: i-quarter
        const int l = tid & 63;
        float4 jb[4];
        float  paj[4];
        #pragma unroll
        for (int m = 0; m < 4; ++m) {
            const int j = bj * 256 + m * 64 + l;
            jb[m]  = sortedBox[j];
            paj[m] = FILT_C * sortedArea[j];
        }
        unsigned int sup[4] = {0u, 0u, 0u, 0u};
        const int kbase = w * 64;
        for (int k = 0; k < 64; ++k) {
            const float4 bo  = tile[kbase + k];
            const float  pai = tpai[kbase + k];
            #pragma unroll
            for (int m = 0; m < 4; ++m) {
                const float iy1 = fmaxf(bo.x, jb[m].x);
                const float ix1 = fmaxf(bo.y, jb[m].y);
                const float iy2 = fminf(bo.z, jb[m].z);
                const float ix2 = fminf(bo.w, jb[m].w);
                const float ih  = fmaxf(iy2 - iy1, 0.0f);
                const float iw  = fmaxf(ix2 - ix1, 0.0f);
                float inter = ih * iw;
                if (fmaf(inter, 1.7f, -(pai + paj[m])) > 0.0f) {
                    float ai = (bo.z - bo.x) * (bo.w - bo.y);
                    float aj = (jb[m].z - jb[m].x) * (jb[m].w - jb[m].y);
                    asm volatile("" : "+v"(ai));
                    asm volatile("" : "+v"(aj));
                    asm volatile("" : "+v"(inter));
                    float s = ai + aj;
                    asm volatile("" : "+v"(s));
                    const float uni = s - inter;
                    sup[m] |= (inter / uni > IOU_THR) ? 1u : 0u;
                }
            }
        }
        #pragma unroll
        for (int m = 0; m < 4; ++m)
            if (sup[m]) atomicOr(&mask[bj * 256 + m * 64 + l], 1u);
    }
}

// ---------------------------------------------------------------------------
// Kernel D: keep = !suppressed; write masked sorted boxes + keep flags.
// d_out layout: [N*4 floats boxes][N floats keep].
// ---------------------------------------------------------------------------
__global__ void nms_output(const float4* __restrict__ sortedBox,
                           const unsigned int* __restrict__ mask,
                           float* __restrict__ out, int N)
{
    const int j = blockIdx.x * 256 + threadIdx.x;
    const float s = (mask[j] == 0u) ? 1.0f : 0.0f;
    const float4 b = sortedBox[j];
    float4 o;
    o.x = b.x * s; o.y = b.y * s; o.z = b.z * s; o.w = b.w * s;
    ((float4*)out)[j] = o;
    out[N * 4 + j] = s;
}

extern "C" void kernel_launch(void* const* d_in, const int* in_sizes, int n_in,
                              void* d_out, int out_size, void* d_ws, size_t ws_size,
                              hipStream_t stream) {
    const float* bbox  = (const float*)d_in[0];   // [1, N, 4] (y1,x1,y2,x2)
    const float* score = (const float*)d_in[1];   // [1, N]
    const int N = in_sizes[1];                    // 8192

    char* ws = (char*)d_ws;
    float4*       sortedBox  = (float4*)ws;                             // N*16 B
    float*        sortedArea = (float*)(ws + (size_t)N * 16);           // N*4 B
    unsigned int* rank       = (unsigned int*)(ws + (size_t)N * 20);    // N*4 B
    unsigned int* mask       = (unsigned int*)(ws + (size_t)N * 24);    // N*4 B

    const int nb = N / 256;

    // zero rank + mask (contiguous) — required every call (graph replay)
    hipMemsetAsync(ws + (size_t)N * 20, 0, (size_t)N * 8, stream);

    nms_rank_partial<<<dim3(N / 1024, nb), 256, 0, stream>>>(score, rank, N);
    nms_scatter<<<nb, 256, 0, stream>>>((const float4*)bbox, rank,
                                        sortedBox, sortedArea);
    nms_suppress<<<nb * (nb + 1) / 2, 256, 0, stream>>>(sortedBox, sortedArea,
                                                        mask);
    nms_output<<<nb, 256, 0, stream>>>(sortedBox, mask, (float*)d_out, N);
}